// Round 1
// baseline (8799.558 us; speedup 1.0000x reference)
//
#include <hip/hip_runtime.h>
#include <cstdint>
#include <cstddef>

#define TT 512
#define BB 128
#define IN_DIM 128
#define HH 512
#define OO 64

#define DECAY  0.8187307530779818f
#define NSCALE 0.2870887f

typedef unsigned short u16;
typedef float f32x4 __attribute__((ext_vector_type(4)));
typedef short bf8 __attribute__((ext_vector_type(8)));

__device__ __forceinline__ u16 f2bf(float f) {
  union { float f; uint32_t u; } v; v.f = f;
  uint32_t r = v.u + 0x7FFFu + ((v.u >> 16) & 1u);
  return (u16)(r >> 16);
}

__device__ __forceinline__ f32x4 mfma16(bf8 a, bf8 b, f32x4 c) {
  return __builtin_amdgcn_mfma_f32_16x16x32_bf16(a, b, c, 0, 0, 0);
}

// ---------------------------------------------------------------------------
// Weight prep: rearrange f32 weights into bf16 MFMA B-fragment order.
// WAF/WBF: [32 j-slices][36 kb][64 lanes][8]  (kb 0..3 = x-term K=128,
//          kb 4..19 = h1-term K=512, kb 20..35 = h2-term K=512)
// WOF:     [8 j-slices][16 kb][64 lanes][8]   (K=512, N=128 = dm|em concat)
// ---------------------------------------------------------------------------
__global__ void wprep_kernel(
    const float* __restrict__ win1, const float* __restrict__ win2,
    const float* __restrict__ w11,  const float* __restrict__ w12,
    const float* __restrict__ w21,  const float* __restrict__ w22,
    const float* __restrict__ wdm,  const float* __restrict__ wem,
    u16* __restrict__ waf, u16* __restrict__ wbf, u16* __restrict__ wof) {
  size_t idx = (size_t)blockIdx.x * 256 + threadIdx.x;
  const size_t NWA = 32u * 36u * 512u;  // 589824
  if (idx < 2 * NWA) {
    int isB = idx >= NWA;
    size_t i = isB ? (idx - NWA) : idx;
    int js  = (int)(i / (36 * 512));
    int rem = (int)(i % (36 * 512));
    int kb  = rem / 512;
    int li  = rem % 512;
    int lane = li >> 3, e = li & 7;
    int j    = js * 16 + (lane & 15);
    int koff = ((lane >> 4) << 3) + e;  // 0..31
    float val;
    if (kb < 4) {
      int k = kb * 32 + koff;                       // 0..127
      val = (isB ? win2 : win1)[(size_t)k * HH + j];
    } else if (kb < 20) {
      int k = (kb - 4) * 32 + koff;                 // 0..511
      val = (isB ? w12 : w11)[(size_t)k * HH + j];
    } else {
      int k = (kb - 20) * 32 + koff;
      val = (isB ? w22 : w21)[(size_t)k * HH + j];
    }
    (isB ? wbf : waf)[i] = f2bf(val);
  } else if (idx < 2 * NWA + 8u * 16u * 512u) {
    size_t i = idx - 2 * NWA;
    int js  = (int)(i / (16 * 512));
    int rem = (int)(i % (16 * 512));
    int kb  = rem / 512;
    int li  = rem % 512;
    int lane = li >> 3, e = li & 7;
    int j = js * 16 + (lane & 15);
    int k = kb * 32 + ((lane >> 4) << 3) + e;       // 0..511
    float val = (j < 64) ? wdm[(size_t)k * OO + j] : wem[(size_t)k * OO + (j - 64)];
    wof[i] = f2bf(val);
  }
}

// ---------------------------------------------------------------------------
// One phase of one timestep.
//   pre = x[t] @ Win + h1 @ Wr1 + h2 @ Wr2 + n(t)     (n = OU noise, updated)
//   h   = 0.9*h + 0.1*sigmoid(pre)
// a_h1 / a_h2: bf16 state mirrors [128][1024] (h1 at cols 0..511, h2 at 512+).
// Phase A (dst_off=0):  a_h1 = a_h2 = HC[in], writes h1 -> HC[out] cols 0..511
// Phase B (dst_off=512): a_h1 = HC[out] (NEW h1), a_h2 = HC[in],
//                        writes h2 -> HC[out] cols 512.., plus hsum[t].
// Grid: 128 wgs x 128 thr. wg: js = bid&31 (16 cols), mg = bid>>5 (32 rows).
// ---------------------------------------------------------------------------
__global__ __launch_bounds__(128) void step_kernel(
    const u16* a_h1, const u16* a_h2, u16* hc_out,
    const float* __restrict__ x,    // [T][B][IN]
    const float* __restrict__ eps,  // [T][B][H]
    const u16* __restrict__ wf,     // [32][36][512]
    float* __restrict__ hf,         // f32 master state [128][512]
    float* __restrict__ nf,         // f32 noise state  [128][512]
    const float* __restrict__ h_other,  // H1F (phase B) or nullptr
    u16* __restrict__ hsum_t,           // &hsum[t][0][0] (phase B) or nullptr
    int t, int dst_off) {
  int js = blockIdx.x & 31;
  int mg = blockIdx.x >> 5;
  int tid = threadIdx.x;
  int w = tid >> 6;
  int l = tid & 63;
  int jc = js * 16;
  int rowbase = mg * 32 + w * 16;

  __shared__ u16 wlds[36 * 512];
  {
    const uint32_t* src = (const uint32_t*)(wf + (size_t)js * (36 * 512));
    uint32_t* dst = (uint32_t*)wlds;
#pragma unroll
    for (int i = 0; i < 72; ++i) dst[tid + i * 128] = src[tid + i * 128];
  }
  __syncthreads();

  int arow = rowbase + (l & 15);
  int kgrp = (l >> 4) * 8;

  f32x4 acc = {0.f, 0.f, 0.f, 0.f};

  // x-term (K = 128): kb 0..3, convert f32 -> bf16 on the fly
  const float* xrow = x + ((size_t)t * BB + arow) * IN_DIM;
#pragma unroll
  for (int kb = 0; kb < 4; ++kb) {
    const float* xp = xrow + kb * 32 + kgrp;
    bf8 af;
#pragma unroll
    for (int e = 0; e < 8; ++e) af[e] = (short)f2bf(xp[e]);
    bf8 bfr = *(const bf8*)(wlds + kb * 512 + l * 8);
    acc = mfma16(af, bfr, acc);
  }
  // h1-term (K = 512): kb 4..19
  {
    const u16* h1row = a_h1 + (size_t)arow * 1024;
#pragma unroll
    for (int kb = 4; kb < 20; ++kb) {
      bf8 af = *(const bf8*)(h1row + (kb - 4) * 32 + kgrp);
      bf8 bfr = *(const bf8*)(wlds + kb * 512 + l * 8);
      acc = mfma16(af, bfr, acc);
    }
  }
  // h2-term (K = 512): kb 20..35
  {
    const u16* h2row = a_h2 + (size_t)arow * 1024 + 512;
#pragma unroll
    for (int kb = 20; kb < 36; ++kb) {
      bf8 af = *(const bf8*)(h2row + (kb - 20) * 32 + kgrp);
      bf8 bfr = *(const bf8*)(wlds + kb * 512 + l * 8);
      acc = mfma16(af, bfr, acc);
    }
  }

  // Epilogue: OU noise update, sigmoid, leaky integration (f32 masters).
  int colg = jc + (l & 15);
  int row0 = rowbase + ((l >> 4) << 2);
#pragma unroll
  for (int r = 0; r < 4; ++r) {
    int row = row0 + r;
    size_t off = (size_t)row * HH + colg;
    float e = eps[((size_t)t * BB + row) * HH + colg];
    float n = nf[off] * DECAY + NSCALE * e;
    float pre = acc[r] + n;
    float s = 1.0f / (1.0f + __expf(-pre));
    float h = hf[off] * 0.9f + 0.1f * s;
    nf[off] = n;
    hf[off] = h;
    hc_out[(size_t)row * 1024 + dst_off + colg] = f2bf(h);
    if (hsum_t) hsum_t[off] = f2bf(h_other[off] + h);
  }
}

// ---------------------------------------------------------------------------
// Output projection: y = hsum[T*B,512] @ Wout[512,128] (dm|em concat), f32 out.
// Grid: 4096 wgs x 256 thr; wg: mg = bid>>2 (64 rows), ng = bid&3 (32 cols).
// ---------------------------------------------------------------------------
__global__ __launch_bounds__(256) void outgemm_kernel(
    const u16* __restrict__ hs, const u16* __restrict__ wof,
    float* __restrict__ out) {
  int ng = blockIdx.x & 3;
  int mg = blockIdx.x >> 2;
  int tid = threadIdx.x;
  int w = tid >> 6, l = tid & 63;

  __shared__ u16 wlds[2 * 16 * 512];
  {
    const uint32_t* src = (const uint32_t*)(wof + (size_t)ng * (2 * 16 * 512));
    uint32_t* dst = (uint32_t*)wlds;
#pragma unroll
    for (int i = 0; i < 32; ++i) dst[tid + i * 256] = src[tid + i * 256];
  }
  __syncthreads();

  int mbase = mg * 64 + w * 16;
  int arow = mbase + (l & 15);
  int kgrp = (l >> 4) * 8;
  const u16* ap = hs + (size_t)arow * HH;

  f32x4 acc0 = {0.f, 0.f, 0.f, 0.f}, acc1 = {0.f, 0.f, 0.f, 0.f};
#pragma unroll
  for (int kb = 0; kb < 16; ++kb) {
    bf8 a = *(const bf8*)(ap + kb * 32 + kgrp);
    bf8 b0 = *(const bf8*)(wlds + kb * 512 + l * 8);
    bf8 b1 = *(const bf8*)(wlds + 8192 + kb * 512 + l * 8);
    acc0 = mfma16(a, b0, acc0);
    acc1 = mfma16(a, b1, acc1);
  }

  int row0 = mbase + ((l >> 4) << 2);
  float* out_em = out + (size_t)TT * BB * OO;
#pragma unroll
  for (int q = 0; q < 2; ++q) {
    f32x4 acc = q ? acc1 : acc0;
    int jg = ng * 32 + q * 16 + (l & 15);
    float* base = (jg < 64) ? out : out_em;
    int col = jg & 63;
#pragma unroll
    for (int r = 0; r < 4; ++r)
      base[(size_t)(row0 + r) * OO + col] = acc[r];
  }
}

// ---------------------------------------------------------------------------
// Workspace layout (bytes):
//   0        HC      2*128*1024*2 = 524288   bf16 state mirrors (dbl-buffered)
//   524288   H1F     262144                  f32 h1 master
//   786432   H2F     262144
//   1048576  N1F     262144                  f32 OU noise state
//   1310720  N2F     262144
//   1572864  WAF     1179648                 frag-arranged weights phase A
//   2752512  WBF     1179648                 phase B
//   3932160  WOF     131072                  output weights
//   4194304  HS      67108864                hsum [T][B][H] bf16
//   total ~71.3 MB
// ---------------------------------------------------------------------------
extern "C" void kernel_launch(void* const* d_in, const int* in_sizes, int n_in,
                              void* d_out, int out_size, void* d_ws, size_t ws_size,
                              hipStream_t stream) {
  const float* x1   = (const float*)d_in[0];
  const float* x2   = (const float*)d_in[1];
  const float* eps1 = (const float*)d_in[2];
  const float* eps2 = (const float*)d_in[3];
  const float* win1 = (const float*)d_in[4];
  const float* win2 = (const float*)d_in[5];
  const float* w11  = (const float*)d_in[6];
  const float* w12  = (const float*)d_in[7];
  const float* w21  = (const float*)d_in[8];
  const float* w22  = (const float*)d_in[9];
  const float* wdm  = (const float*)d_in[10];
  const float* wem  = (const float*)d_in[11];

  char* ws = (char*)d_ws;
  u16*   HC  = (u16*)(ws + 0);
  float* H1F = (float*)(ws + 524288);
  float* H2F = (float*)(ws + 786432);
  float* N1F = (float*)(ws + 1048576);
  float* N2F = (float*)(ws + 1310720);
  u16*   WAF = (u16*)(ws + 1572864);
  u16*   WBF = (u16*)(ws + 2752512);
  u16*   WOF = (u16*)(ws + 3932160);
  u16*   HS  = (u16*)(ws + 4194304);

  // zero the recurrent state (h(-1)=0, n(-1)=0)
  hipMemsetAsync(ws, 0, 1572864, stream);

  wprep_kernel<<<4864, 256, 0, stream>>>(win1, win2, w11, w12, w21, w22,
                                         wdm, wem, WAF, WBF, WOF);

  for (int t = 0; t < TT; ++t) {
    u16* hin  = HC + (size_t)(t & 1) * 131072;
    u16* hout = HC + (size_t)((t + 1) & 1) * 131072;
    // Phase A: h1(t) from h1(t-1), h2(t-1)
    step_kernel<<<128, 128, 0, stream>>>(hin, hin, hout, x1, eps1, WAF,
                                         H1F, N1F, nullptr, nullptr, t, 0);
    // Phase B: h2(t) from NEW h1(t) and h2(t-1); also emits hsum[t]
    step_kernel<<<128, 128, 0, stream>>>(hout, hin, hout, x2, eps2, WBF,
                                         H2F, N2F, H1F,
                                         HS + (size_t)t * BB * HH, t, 512);
  }

  outgemm_kernel<<<4096, 256, 0, stream>>>(HS, WOF, (float*)d_out);
}